// Round 1
// baseline (555.906 us; speedup 1.0000x reference)
//
#include <hip/hip_runtime.h>

// DCT-II 2D (ortho) = D @ X @ D^T per 1024x1024 image, 48 images.
// Both stages are the same GEMM: out = transpose(M @ D^T), transpose done
// free via mfma operand swap (mfma(b,a,acc) -> C^T in standard C/D layout).

typedef __bf16 bf16_t;
typedef __bf16 bf16x4 __attribute__((ext_vector_type(4)));
typedef __bf16 bf16x8 __attribute__((ext_vector_type(8)));
typedef float  f32x4  __attribute__((ext_vector_type(4)));

#define GLDS16(g, l) \
    __builtin_amdgcn_global_load_lds((__attribute__((address_space(1))) void*)(g), \
                                     (__attribute__((address_space(3))) void*)(l), 16, 0, 0)

// ---- generate bf16 DCT matrix D[k][n] = s_k * cos(pi*(2n+1)*k/2048) ----
// phase reduced exactly: ((2n+1)*k) mod 4096 -> angle in [0, 2pi)
__global__ __launch_bounds__(256) void gen_dmat(bf16_t* __restrict__ D) {
    int idx = (blockIdx.x * 256 + threadIdx.x) * 4;   // 4 consecutive elems, same row k
    int k = idx >> 10;
    int n0 = idx & 1023;
    float s = (k == 0) ? 0.03125f : 0.04419417382415922f;  // 1/32, sqrt(2)/32
#pragma unroll
    for (int j = 0; j < 4; ++j) {
        int n = n0 + j;
        int t = ((2 * n + 1) * k) & 4095;
        float ang = (float)t * 1.5339807878856412e-3f;      // pi/2048
        D[idx + j] = (bf16_t)(__cosf(ang) * s);
    }
}

// ---- GEMM: Z = transpose(A @ D^T), A is [1024][1024] per batch ----
// A_F32: A is fp32 (convert to bf16 during LDS staging, padded tile)
//        else bf16 staged via global_load_lds (packed tile)
// OUT_F32: write fp32, else bf16
template <bool A_F32, bool OUT_F32>
__global__ __launch_bounds__(256, 3) void dct_gemm(const void* __restrict__ Ain,
                                                   const bf16_t* __restrict__ Dmat,
                                                   void* __restrict__ Out) {
    constexpr int LDA = A_F32 ? 40 : 32;   // +8 pad allowed only on register path
    __shared__ bf16_t As[128 * LDA];
    __shared__ bf16_t Bs[128 * 32];

    const int tid  = threadIdx.x;
    const int lane = tid & 63;
    const int wv   = tid >> 6;
    const int wm   = (wv & 1) * 64;    // wave's m-offset in 128x128 tile
    const int wn   = (wv >> 1) * 64;   // wave's n-offset
    const int l15  = lane & 15;
    const int quad = lane >> 4;

    const int m0 = blockIdx.x * 128;   // rows of A
    const int n0 = blockIdx.y * 128;   // rows of D (output freq)
    const size_t img = (size_t)1024 * 1024;
    const size_t boff = (size_t)blockIdx.z * img;

    f32x4 acc[4][4];
#pragma unroll
    for (int i = 0; i < 4; ++i)
#pragma unroll
        for (int j = 0; j < 4; ++j)
            acc[i][j] = (f32x4){0.f, 0.f, 0.f, 0.f};

    const bf16_t* Bg   = Dmat + (size_t)n0 * 1024;
    const bf16_t* Ag_b = A_F32 ? nullptr : ((const bf16_t*)Ain + boff + (size_t)m0 * 1024);
    const float*  Ag_f = A_F32 ? ((const float*)Ain + boff + (size_t)m0 * 1024) : nullptr;

    for (int k0 = 0; k0 < 1024; k0 += 32) {
        __syncthreads();   // previous iter's compute done before overwrite
        // ---- stage B tile (D rows, bf16, packed): 512 x 16B chunks ----
#pragma unroll
        for (int i = 0; i < 2; ++i) {
            int c = tid + i * 256;
            const bf16_t* src = Bg + (size_t)(c >> 2) * 1024 + k0 + (c & 3) * 8;
            GLDS16(src, &Bs[c * 8]);
        }
        // ---- stage A tile ----
        if constexpr (A_F32) {
            // 128x32 fp32 -> bf16, 1024 float4 chunks, 4/thread
#pragma unroll
            for (int i = 0; i < 4; ++i) {
                int c = tid + i * 256;
                int row = c >> 3, c4 = c & 7;
                const float4 v = *(const float4*)(Ag_f + (size_t)row * 1024 + k0 + c4 * 4);
                bf16x4 bv;
                bv[0] = (bf16_t)v.x; bv[1] = (bf16_t)v.y;
                bv[2] = (bf16_t)v.z; bv[3] = (bf16_t)v.w;
                *(bf16x4*)&As[row * LDA + c4 * 4] = bv;
            }
        } else {
#pragma unroll
            for (int i = 0; i < 2; ++i) {
                int c = tid + i * 256;
                const bf16_t* src = Ag_b + (size_t)(c >> 2) * 1024 + k0 + (c & 3) * 8;
                GLDS16(src, &As[c * 8]);
            }
        }
        __syncthreads();   // drains vmcnt before use

        bf16x8 af[4], bf[4];
#pragma unroll
        for (int i = 0; i < 4; ++i)
            af[i] = *(const bf16x8*)&As[(wm + i * 16 + l15) * LDA + quad * 8];
#pragma unroll
        for (int j = 0; j < 4; ++j)
            bf[j] = *(const bf16x8*)&Bs[(wn + j * 16 + l15) * 32 + quad * 8];

        // operand swap: result is C^T tile in standard C/D layout
#pragma unroll
        for (int i = 0; i < 4; ++i)
#pragma unroll
            for (int j = 0; j < 4; ++j)
                acc[i][j] = __builtin_amdgcn_mfma_f32_16x16x32_bf16(bf[j], af[i], acc[i][j], 0, 0, 0);
    }

    // ---- epilogue: Z[n][m] (= C^T), row = n0+wn+j*16+quad*4+r, col = m0+wm+i*16+l15
    if constexpr (OUT_F32) {
        float* Og = (float*)Out + boff;
#pragma unroll
        for (int j = 0; j < 4; ++j) {
            int zr0 = n0 + wn + j * 16 + quad * 4;
#pragma unroll
            for (int r = 0; r < 4; ++r) {
                float* orow = Og + (size_t)(zr0 + r) * 1024 + m0 + wm + l15;
#pragma unroll
                for (int i = 0; i < 4; ++i)
                    orow[i * 16] = acc[i][j][r];
            }
        }
    } else {
        bf16_t* Og = (bf16_t*)Out + boff;
#pragma unroll
        for (int j = 0; j < 4; ++j) {
            int zr0 = n0 + wn + j * 16 + quad * 4;
#pragma unroll
            for (int r = 0; r < 4; ++r) {
                bf16_t* orow = Og + (size_t)(zr0 + r) * 1024 + m0 + wm + l15;
#pragma unroll
                for (int i = 0; i < 4; ++i)
                    orow[i * 16] = (bf16_t)acc[i][j][r];
            }
        }
    }
}

extern "C" void kernel_launch(void* const* d_in, const int* in_sizes, int n_in,
                              void* d_out, int out_size, void* d_ws, size_t ws_size,
                              hipStream_t stream) {
    (void)in_sizes; (void)n_in; (void)out_size; (void)ws_size;
    const float* X = (const float*)d_in[0];
    float* Y = (float*)d_out;

    // ws layout: [0,2MB) D bf16 ; [2MB, 2MB+48*1M*2) V^T bf16  (~102.7 MB total)
    bf16_t* Dm = (bf16_t*)d_ws;
    bf16_t* Vt = (bf16_t*)((char*)d_ws + ((size_t)1024 * 1024 * 2));

    gen_dmat<<<1024, 256, 0, stream>>>(Dm);

    dim3 grid(8, 8, 48), block(256);
    // stage 1: V^T = (X @ D^T)^T   (DCT along width, transposed store)
    dct_gemm<true, false><<<grid, block, 0, stream>>>((const void*)X, Dm, (void*)Vt);
    // stage 2: Y = (V^T @ D^T)^T   (DCT along height, lands row-major)
    dct_gemm<false, true><<<grid, block, 0, stream>>>((const void*)Vt, Dm, (void*)Y);
}